// Round 6
// baseline (321.657 us; speedup 1.0000x reference)
//
#include <hip/hip_runtime.h>
#include <hip/hip_bf16.h>
#include <hip/hip_fp16.h>
#include <stdint.h>

// ---------------------------------------------------------------------------
// GCN forward on MI355X.
//   CSR build via 196-bucket counting sort (bucket = col>>9, 512 nodes each).
//     k_bhist   : GS=1024 chunked edge scan, LDS hist -> cntmat[g][b]
//     k_colscan : per-bucket exclusive scan of cntmat column over g
//     k_bscan   : exclusive scan of bucket totals -> bbase
//     k_scat_xf : heterogeneous-role fused kernel, grid=1536 (6 blocks/CU).
//                 span of 6 blocks: 4 scatter-role + 2 transform-role.
//                 ROUND-5 LESSON: scatter at 2 blocks/CU is latency-bound
//                 (~105 cyc/edge/wave, HBM 11%, VALU 21%, occ 24% -- nothing
//                 saturated; arrangement-invariant across rounds 3/4/5).
//                 This round: 4 scatter blocks/CU (2x waves on the dependent
//                 load->LDS-atomic->scattered-store chain), 2 transform
//                 blocks/CU (x-stream still hides under scatter).
//                 chunk = E/1024 -> per-bucket write runs = 32 edges = 128B
//                 (still above the 32B cross-XCD partial-line regime that
//                 caused the round-3 regression).
//     k_pass2   : one block per bucket (512 thr): LDS 512-hist of sorted
//                 slice -> LDS scan -> rowptr = bbase[b]+prefix, dis =
//                 rsqrt(deg+1), scale t1raw *= dis, cursor-fill csr.
//   Layers (agg commutes with dense: A(XW)=(AX)W; all gathers width 16; the
//   16->32->16 chain and the classifier are fused into agg epilogues via
//   16-lane shuffle broadcasts -- h2 is never materialized):
//     t1  = (x @ W1) * dis                        (k_scat_xf + k_pass2)
//     hs1 = relu(dis*gather(t1) + b1) * dis       (k_agg_rb)
//     t3  = (relu((dis*gather(hs1))@W2+b2)@W3)*dis (k_agg_mid, fused)
//     h   = relu(dis*gather(t3) + b3) -> outh
//     out = h @ Wc + bc               -> outc      (k_agg_out, fused)
//   Gathered arrays (t1, hs1, t3) are stored FP16: 3.2MB each -> fits the
//   4MB per-XCD L2. Random row reads are 32B, accumulation fp32. gather is
//   16-edge unrolled with 4 independent accumulators (~16 lines in flight).
//   No fp atomics anywhere. 8 kernel launches total.
// ---------------------------------------------------------------------------

__device__ __forceinline__ int blockScanExclusive256(int v, int* wsum) {
  int lane = threadIdx.x & 63;
  int wid  = threadIdx.x >> 6;
  int inc = v;
#pragma unroll
  for (int d = 1; d < 64; d <<= 1) {
    int y = __shfl_up(inc, d, 64);
    if (lane >= d) inc += y;
  }
  if (lane == 63) wsum[wid] = inc;
  __syncthreads();
  if (threadIdx.x == 0) {
    int s = 0;
#pragma unroll
    for (int w = 0; w < 4; ++w) { int t = wsum[w]; wsum[w] = s; s += t; }
  }
  __syncthreads();
  return inc - v + wsum[wid];
}

__device__ __forceinline__ int blockScanExclusive512(int v, int* wsum) {
  int lane = threadIdx.x & 63;
  int wid  = threadIdx.x >> 6;  // 0..7
  int inc = v;
#pragma unroll
  for (int d = 1; d < 64; d <<= 1) {
    int y = __shfl_up(inc, d, 64);
    if (lane >= d) inc += y;
  }
  if (lane == 63) wsum[wid] = inc;
  __syncthreads();
  if (threadIdx.x == 0) {
    int s = 0;
#pragma unroll
    for (int w = 0; w < 8; ++w) { int t = wsum[w]; wsum[w] = s; s += t; }
  }
  __syncthreads();
  return inc - v + wsum[wid];
}

// ---- per-block bucket histogram -> cntmat[g*nb + b] (g-major) ----
__global__ __launch_bounds__(256) void k_bhist(const int* __restrict__ ecol,
                                               int* __restrict__ cntmat,
                                               int e, int chunk, int nb) {
  __shared__ int h[256];
  h[threadIdx.x] = 0;
  __syncthreads();
  int g = blockIdx.x;
  int s0 = g * chunk;
  int s1 = min(e, s0 + chunk);
  int i = s0 + threadIdx.x;
  for (; i + 768 < s1; i += 1024) {
    int c0 = ecol[i], c1 = ecol[i + 256], c2 = ecol[i + 512], c3 = ecol[i + 768];
    atomicAdd(&h[c0 >> 9], 1);
    atomicAdd(&h[c1 >> 9], 1);
    atomicAdd(&h[c2 >> 9], 1);
    atomicAdd(&h[c3 >> 9], 1);
  }
  for (; i < s1; i += 256) atomicAdd(&h[ecol[i] >> 9], 1);
  __syncthreads();
  for (int b = threadIdx.x; b < nb; b += 256) cntmat[g * nb + b] = h[b];
}

// ---- per-bucket column scan over g; column total -> colsum[b] ----
__global__ __launch_bounds__(256) void k_colscan(int* __restrict__ cntmat,
                                                 int* __restrict__ colsum,
                                                 int G, int nb) {
  __shared__ int wsum[4];
  __shared__ int carry_s;
  int b = blockIdx.x;
  if (threadIdx.x == 0) carry_s = 0;
  __syncthreads();
  for (int base = 0; base < G; base += 256) {
    int i = base + threadIdx.x;
    int v = (i < G) ? cntmat[i * nb + b] : 0;
    int ex = blockScanExclusive256(v, wsum);
    int c = carry_s;
    __syncthreads();
    if (i < G) cntmat[i * nb + b] = ex + c;
    if (threadIdx.x == 255) carry_s = c + ex + v;
    __syncthreads();
  }
  if (threadIdx.x == 0) colsum[b] = carry_s;
}

// ---- bucket exclusive scan (1 block) ----
__global__ __launch_bounds__(256) void k_bscan(const int* __restrict__ colsum,
                                               int* __restrict__ bbase,
                                               int nb, int etot) {
  __shared__ int wsum[4];
  __shared__ int carry_s;
  if (threadIdx.x == 0) carry_s = 0;
  __syncthreads();
  for (int base = 0; base < nb; base += 256) {
    int i = base + threadIdx.x;
    int v = (i < nb) ? colsum[i] : 0;
    int ex = blockScanExclusive256(v, wsum);
    int c = carry_s;
    __syncthreads();
    if (i < nb) bbase[i] = ex + c;
    if (threadIdx.x == 255) carry_s = c + ex + v;
    __syncthreads();
  }
  if (threadIdx.x == 0) bbase[nb] = etot;
}

// ---- role-interleaved: per 6-block span, blocks 0-3 scatter, 4-5 xform ----
__global__ __launch_bounds__(256) void k_scat_xf(
    const int* __restrict__ erow, const int* __restrict__ ecol,
    const int* __restrict__ cntmat, const int* __restrict__ bbase,
    unsigned* __restrict__ sorted, int e, int chunk, int nb,
    const float* __restrict__ x, const float* __restrict__ W,
    __half* __restrict__ t1raw, int n) {
  int span = blockIdx.x / 6;
  int w6   = blockIdx.x % 6;
  if (w6 < 4) {
    // ------------- scatter role (g = span*4 + w6, 0..1023) -------------
    __shared__ int base[256];
    int g = span * 4 + w6;
    for (int b = threadIdx.x; b < nb; b += 256)
      base[b] = bbase[b] + cntmat[g * nb + b];  // contiguous 784B read
    __syncthreads();
    int s0 = g * chunk;
    int s1 = min(e, s0 + chunk);
    int i = s0 + threadIdx.x;
    for (; i + 1792 < s1; i += 2048) {
      int c0 = ecol[i],        c1 = ecol[i + 256],  c2 = ecol[i + 512],  c3 = ecol[i + 768];
      int c4 = ecol[i + 1024], c5 = ecol[i + 1280], c6 = ecol[i + 1536], c7 = ecol[i + 1792];
      int r0 = erow[i],        r1 = erow[i + 256],  r2 = erow[i + 512],  r3 = erow[i + 768];
      int r4 = erow[i + 1024], r5 = erow[i + 1280], r6 = erow[i + 1536], r7 = erow[i + 1792];
      int p0 = atomicAdd(&base[c0 >> 9], 1);
      int p1 = atomicAdd(&base[c1 >> 9], 1);
      int p2 = atomicAdd(&base[c2 >> 9], 1);
      int p3 = atomicAdd(&base[c3 >> 9], 1);
      int p4 = atomicAdd(&base[c4 >> 9], 1);
      int p5 = atomicAdd(&base[c5 >> 9], 1);
      int p6 = atomicAdd(&base[c6 >> 9], 1);
      int p7 = atomicAdd(&base[c7 >> 9], 1);
      sorted[p0] = ((unsigned)r0 << 9) | (unsigned)(c0 & 511);
      sorted[p1] = ((unsigned)r1 << 9) | (unsigned)(c1 & 511);
      sorted[p2] = ((unsigned)r2 << 9) | (unsigned)(c2 & 511);
      sorted[p3] = ((unsigned)r3 << 9) | (unsigned)(c3 & 511);
      sorted[p4] = ((unsigned)r4 << 9) | (unsigned)(c4 & 511);
      sorted[p5] = ((unsigned)r5 << 9) | (unsigned)(c5 & 511);
      sorted[p6] = ((unsigned)r6 << 9) | (unsigned)(c6 & 511);
      sorted[p7] = ((unsigned)r7 << 9) | (unsigned)(c7 & 511);
    }
    for (; i < s1; i += 256) {
      int c = ecol[i];
      int p = atomicAdd(&base[c >> 9], 1);
      sorted[p] = ((unsigned)erow[i] << 9) | (unsigned)(c & 511);
    }
    return;
  }

  // ------------- transform role (t = span*2 + w6-4, 0..511) -------------
  int L = threadIdx.x & 63;
  int t = span * 2 + (w6 - 4);
  int wid = t * 4 + (threadIdx.x >> 6);
  int nw = (gridDim.x / 6) * 2 * 4;

  float w[8][16];
  const float4* W4 = reinterpret_cast<const float4*>(W);
#pragma unroll
  for (int i = 0; i < 4; ++i) {
#pragma unroll
    for (int c4 = 0; c4 < 4; ++c4) {
      float4 va = W4[(4 * L + i) * 4 + c4];
      w[i][c4 * 4 + 0] = va.x; w[i][c4 * 4 + 1] = va.y;
      w[i][c4 * 4 + 2] = va.z; w[i][c4 * 4 + 3] = va.w;
      float4 vb = W4[(256 + 4 * L + i) * 4 + c4];
      w[4 + i][c4 * 4 + 0] = vb.x; w[4 + i][c4 * 4 + 1] = vb.y;
      w[4 + i][c4 * 4 + 2] = vb.z; w[4 + i][c4 * 4 + 3] = vb.w;
    }
  }
  int col = ((L & 1) << 3) | ((L & 2) << 1) | ((L & 4) >> 1) | ((L & 8) >> 3);

  for (int r = wid; r < n; r += nw) {
    const float4* xr = reinterpret_cast<const float4*>(x + (size_t)r * 512);
    float4 v0 = xr[L];
    float4 v1 = xr[64 + L];
    float acc[16];
#pragma unroll
    for (int c = 0; c < 16; ++c) {
      float a = v0.x * w[0][c];
      a = fmaf(v0.y, w[1][c], a);
      a = fmaf(v0.z, w[2][c], a);
      a = fmaf(v0.w, w[3][c], a);
      a = fmaf(v1.x, w[4][c], a);
      a = fmaf(v1.y, w[5][c], a);
      a = fmaf(v1.z, w[6][c], a);
      a = fmaf(v1.w, w[7][c], a);
      acc[c] = a;
    }
#pragma unroll
    for (int j = 0; j < 8; ++j) {
      float send = (L & 1) ? acc[j] : acc[j + 8];
      float recv = __shfl_xor(send, 1, 64);
      acc[j] = ((L & 1) ? acc[j + 8] : acc[j]) + recv;
    }
#pragma unroll
    for (int j = 0; j < 4; ++j) {
      float send = (L & 2) ? acc[j] : acc[j + 4];
      float recv = __shfl_xor(send, 2, 64);
      acc[j] = ((L & 2) ? acc[j + 4] : acc[j]) + recv;
    }
#pragma unroll
    for (int j = 0; j < 2; ++j) {
      float send = (L & 4) ? acc[j] : acc[j + 2];
      float recv = __shfl_xor(send, 4, 64);
      acc[j] = ((L & 4) ? acc[j + 2] : acc[j]) + recv;
    }
    {
      float send = (L & 8) ? acc[0] : acc[1];
      float recv = __shfl_xor(send, 8, 64);
      acc[0] = ((L & 8) ? acc[1] : acc[0]) + recv;
    }
    float s = acc[0];
    s += __shfl_xor(s, 16, 64);
    s += __shfl_xor(s, 32, 64);
    if (L < 16) t1raw[r * 16 + col] = __float2half(s);
  }
}

// ---- pass2: per-bucket hist + scan + rowptr/dis + t1 scale + csr fill ----
__global__ __launch_bounds__(512) void k_pass2(const unsigned* __restrict__ sorted,
                                               const int* __restrict__ bbase,
                                               float* __restrict__ dis,
                                               int* __restrict__ rowptr,
                                               __half* __restrict__ t1,
                                               int* __restrict__ csr,
                                               int n, int etot) {
  __shared__ int hist[512];
  __shared__ int cur[512];
  __shared__ int wsum[8];
  int b = blockIdx.x;
  hist[threadIdx.x] = 0;
  __syncthreads();
  int s0 = bbase[b], s1 = bbase[b + 1];
  for (int i = s0 + threadIdx.x; i < s1; i += 512)
    atomicAdd(&hist[sorted[i] & 511], 1);
  __syncthreads();
  int j = threadIdx.x;
  int node = (b << 9) + j;
  int deg = hist[j];
  int ex = blockScanExclusive512(deg, wsum);
  float dv = rsqrtf((float)(deg + 1));  // +1 self loop
  cur[j] = s0 + ex;
  if (node < n) {
    dis[node] = dv;
    rowptr[node] = s0 + ex;
    // scale this node's t1 row in place (bucket rows contiguous, streaming)
    __half2* t2 = reinterpret_cast<__half2*>(t1 + ((size_t)node << 4));
#pragma unroll
    for (int q = 0; q < 8; ++q) {
      float2 fv = __half22float2(t2[q]);
      fv.x *= dv; fv.y *= dv;
      t2[q] = __float22half2_rn(fv);
    }
  }
  if (b == 0 && threadIdx.x == 0) rowptr[n] = etot;
  __syncthreads();
  for (int i = s0 + threadIdx.x; i < s1; i += 512) {
    unsigned v = sorted[i];
    int pos = atomicAdd(&cur[v & 511], 1);
    csr[pos] = (int)(v >> 9);
  }
}

// ---- common gather: acc = self + sum of neighbor rows (fp16 rows, fp32
//      accumulate). 16-edge unroll, 4 independent accumulators: ~16
//      independent 32B row-loads in flight per wave iteration. ----
__device__ __forceinline__ float gather16(const __half* __restrict__ hs,
                                          const int* __restrict__ rowptr,
                                          const int* __restrict__ csr,
                                          int node, int f) {
  float acc0 = __half2float(hs[(node << 4) + f]);  // self loop (pre-scaled)
  int e0 = rowptr[node], e1 = rowptr[node + 1];
  int e = e0;
  float acc1 = 0.f, acc2 = 0.f, acc3 = 0.f;
  for (; e + 16 <= e1; e += 16) {
    int r0  = csr[e + 0],  r1  = csr[e + 1],  r2  = csr[e + 2],  r3  = csr[e + 3];
    int r4  = csr[e + 4],  r5  = csr[e + 5],  r6  = csr[e + 6],  r7  = csr[e + 7];
    int r8  = csr[e + 8],  r9  = csr[e + 9],  r10 = csr[e + 10], r11 = csr[e + 11];
    int r12 = csr[e + 12], r13 = csr[e + 13], r14 = csr[e + 14], r15 = csr[e + 15];
    __half v0  = hs[(r0  << 4) + f], v1  = hs[(r1  << 4) + f];
    __half v2  = hs[(r2  << 4) + f], v3  = hs[(r3  << 4) + f];
    __half v4  = hs[(r4  << 4) + f], v5  = hs[(r5  << 4) + f];
    __half v6  = hs[(r6  << 4) + f], v7  = hs[(r7  << 4) + f];
    __half v8  = hs[(r8  << 4) + f], v9  = hs[(r9  << 4) + f];
    __half v10 = hs[(r10 << 4) + f], v11 = hs[(r11 << 4) + f];
    __half v12 = hs[(r12 << 4) + f], v13 = hs[(r13 << 4) + f];
    __half v14 = hs[(r14 << 4) + f], v15 = hs[(r15 << 4) + f];
    acc0 += (__half2float(v0)  + __half2float(v1))  + (__half2float(v2)  + __half2float(v3));
    acc1 += (__half2float(v4)  + __half2float(v5))  + (__half2float(v6)  + __half2float(v7));
    acc2 += (__half2float(v8)  + __half2float(v9))  + (__half2float(v10) + __half2float(v11));
    acc3 += (__half2float(v12) + __half2float(v13)) + (__half2float(v14) + __half2float(v15));
  }
  for (; e + 4 <= e1; e += 4) {
    int r0 = csr[e + 0], r1 = csr[e + 1], r2 = csr[e + 2], r3 = csr[e + 3];
    float v0 = __half2float(hs[(r0 << 4) + f]), v1 = __half2float(hs[(r1 << 4) + f]);
    float v2 = __half2float(hs[(r2 << 4) + f]), v3 = __half2float(hs[(r3 << 4) + f]);
    acc0 += (v0 + v1) + (v2 + v3);
  }
  for (; e < e1; ++e) acc0 += __half2float(hs[(csr[e] << 4) + f]);
  return (acc0 + acc1) + (acc2 + acc3);
}

// out = relu(dis*acc + b) * dis   (layer-1 agg, prescaled for next gather)
__global__ __launch_bounds__(256) void k_agg_rb(
    const __half* __restrict__ hs, const int* __restrict__ rowptr,
    const int* __restrict__ csr, const float* __restrict__ dis,
    const float* __restrict__ b, __half* __restrict__ out, int n) {
  int node = blockIdx.x * 16 + threadIdx.x / 16;
  int f = threadIdx.x % 16;
  if (node >= n) return;
  float acc = gather16(hs, rowptr, csr, node, f);
  float d = dis[node];
  float t = fmaxf(fmaf(d, acc, b[f]), 0.f);
  out[(node << 4) + f] = __float2half(t * d);
}

// mid: t3 = (relu((dis*acc)@W2 + b2) @ W3) * dis   -- 16->32->16 in-register
__global__ __launch_bounds__(256) void k_agg_mid(
    const __half* __restrict__ hs, const int* __restrict__ rowptr,
    const int* __restrict__ csr, const float* __restrict__ dis,
    const float* __restrict__ W2, const float* __restrict__ b2,
    const float* __restrict__ W3, __half* __restrict__ out, int n) {
  __shared__ float w2s[512];  // [16][32]
  __shared__ float w3s[512];  // [32][16]
  __shared__ float b2s[32];
  for (int i = threadIdx.x; i < 512; i += 256) { w2s[i] = W2[i]; w3s[i] = W3[i]; }
  if (threadIdx.x < 32) b2s[threadIdx.x] = b2[threadIdx.x];
  __syncthreads();
  int node = blockIdx.x * 16 + threadIdx.x / 16;
  int f = threadIdx.x % 16;
  if (node >= n) return;
  float acc = gather16(hs, rowptr, csr, node, f);
  float d = dis[node];
  float v = d * acc;  // g2[f]
  int base = threadIdx.x & 48;  // 16-group base lane in wave
  float a0 = b2s[f], a1 = b2s[f + 16];
#pragma unroll
  for (int k = 0; k < 16; ++k) {
    float vk = __shfl(v, base + k, 64);
    a0 = fmaf(vk, w2s[k * 32 + f], a0);
    a1 = fmaf(vk, w2s[k * 32 + 16 + f], a1);
  }
  a0 = fmaxf(a0, 0.f);
  a1 = fmaxf(a1, 0.f);
  float t = 0.f;
#pragma unroll
  for (int c = 0; c < 16; ++c) {
    float h0 = __shfl(a0, base + c, 64);
    float h1 = __shfl(a1, base + c, 64);
    t = fmaf(h0, w3s[c * 16 + f], t);
    t = fmaf(h1, w3s[(c + 16) * 16 + f], t);
  }
  out[(node << 4) + f] = __float2half(t * d);
}

// final: h = relu(dis*acc + b3) -> outh;  out = h@Wc + bc -> outc
__global__ __launch_bounds__(256) void k_agg_out(
    const __half* __restrict__ hs, const int* __restrict__ rowptr,
    const int* __restrict__ csr, const float* __restrict__ dis,
    const float* __restrict__ b3, const float* __restrict__ Wc,
    const float* __restrict__ bc, float* __restrict__ outh,
    float* __restrict__ outc, int n) {
  __shared__ float wcs[256];  // [16][16]
  __shared__ float b3s[16];
  __shared__ float bcs[16];
  if (threadIdx.x < 256) wcs[threadIdx.x] = Wc[threadIdx.x];
  if (threadIdx.x < 16) { b3s[threadIdx.x] = b3[threadIdx.x]; bcs[threadIdx.x] = bc[threadIdx.x]; }
  __syncthreads();
  int node = blockIdx.x * 16 + threadIdx.x / 16;
  int f = threadIdx.x % 16;
  if (node >= n) return;
  float acc = gather16(hs, rowptr, csr, node, f);
  float d = dis[node];
  float h = fmaxf(fmaf(d, acc, b3s[f]), 0.f);
  outh[(node << 4) + f] = h;
  int base = threadIdx.x & 48;
  float o = bcs[f];
#pragma unroll
  for (int k = 0; k < 16; ++k) {
    float hk = __shfl(h, base + k, 64);
    o = fmaf(hk, wcs[k * 16 + f], o);
  }
  outc[(node << 4) + f] = o;
}

extern "C" void kernel_launch(void* const* d_in, const int* in_sizes, int n_in,
                              void* d_out, int out_size, void* d_ws, size_t ws_size,
                              hipStream_t stream) {
  (void)n_in; (void)out_size;
  const float* x  = (const float*)d_in[0];
  const int*   ei = (const int*)d_in[1];
  const float* W1 = (const float*)d_in[2];
  const float* b1 = (const float*)d_in[3];
  const float* W2 = (const float*)d_in[4];
  const float* b2 = (const float*)d_in[5];
  const float* W3 = (const float*)d_in[6];
  const float* b3 = (const float*)d_in[7];
  const float* Wc = (const float*)d_in[8];
  const float* bc = (const float*)d_in[9];

  const int F = 512;
  int N = in_sizes[0] / F;
  int E = in_sizes[1] / 2;
  const int* erow = ei;        // sources
  const int* ecol = ei + E;    // targets
  int NB = (N + 511) >> 9;     // buckets of 512 nodes (N<=131072)
  const int GS = 1024;         // scatter blocks: chunk=E/1024 -> 128B runs
  const int GRID = 1536;       // 1024 scatter + 512 transform, 6 blocks/CU
  int chunk = (E + GS - 1) / GS;

  auto align = [](size_t v) { return (v + 255) & ~(size_t)255; };
  char* p = (char*)d_ws;
  int*   cntmat = (int*)p;   p += align((size_t)GS * NB * 4);
  int*   colsum = (int*)p;   p += align(256 * 4);
  int*   bbase  = (int*)p;   p += align(257 * 4);
  float* dis    = (float*)p; p += align((size_t)N * 4);
  int*   rowptr = (int*)p;   p += align(((size_t)N + 1) * 4);
  int*   csr    = (int*)p;   p += align((size_t)E * 4);
  unsigned* sorted = (unsigned*)p; p += align((size_t)E * 4);
  // bufA does not alias sorted (sorted is live while t1 is written)
  __half* bufA = (__half*)p; p += align((size_t)N * 16 * 2);
  __half* bufB = (__half*)p; p += align((size_t)N * 16 * 2);
  if ((size_t)(p - (char*)d_ws) > ws_size) return;  // fail visibly

  float* outc = (float*)d_out;                   // [N,16] classifier out
  float* outh = (float*)d_out + (size_t)N * 16;  // [N,16] h

  // ---- CSR build + fused layer-1 transform ----
  k_bhist<<<GS, 256, 0, stream>>>(ecol, cntmat, E, chunk, NB);
  k_colscan<<<NB, 256, 0, stream>>>(cntmat, colsum, GS, NB);
  k_bscan<<<1, 256, 0, stream>>>(colsum, bbase, NB, E);
  // role-interleaved: 6-block spans of 4 scatter + 2 transform
  k_scat_xf<<<GRID, 256, 0, stream>>>(erow, ecol, cntmat, bbase, sorted, E,
                                      chunk, NB, x, W1, bufA, N);
  // hist+scan+rowptr+dis, t1 *= dis, csr fill
  k_pass2<<<NB, 512, 0, stream>>>(sorted, bbase, dis, rowptr, bufA, csr, N, E);

  // ---- layers ----
  // hs1 = relu(dis*agg(t1)+b1)*dis  (fp16)
  k_agg_rb<<<(N + 15) / 16, 256, 0, stream>>>(bufA, rowptr, csr, dis, b1, bufB, N);
  // t3 = (relu((dis*agg(hs1))@W2+b2)@W3)*dis  (fp16)
  k_agg_mid<<<(N + 15) / 16, 256, 0, stream>>>(bufB, rowptr, csr, dis, W2, b2, W3, bufA, N);
  // h = relu(dis*agg(t3)+b3) -> outh;  out = h@Wc+bc -> outc  (fp32 outputs)
  k_agg_out<<<(N + 15) / 16, 256, 0, stream>>>(bufA, rowptr, csr, dis, b3, Wc, bc, outh, outc, N);
}

// Round 7
// 311.811 us; speedup vs baseline: 1.0316x; 1.0316x over previous
//
#include <hip/hip_runtime.h>
#include <hip/hip_bf16.h>
#include <hip/hip_fp16.h>
#include <stdint.h>

// ---------------------------------------------------------------------------
// GCN forward on MI355X.
//   CSR build via 196-bucket counting sort (bucket = col>>9, 512 nodes each).
//     k_bhist      : GS-chunk edge scan, LDS hist -> cntmat[g][b]
//     k_colscan    : per-bucket exclusive scan of cntmat column over g
//     k_bscan      : exclusive scan of bucket totals -> bbase
//     k_scatter_ms : LDS MULTISPLIT scatter. ROUNDS 3-6 LESSON: direct
//                    scattered 4B stores hit a per-CU divergent-store wall
//                    (~14 cyc/lane; 6.4M edges -> ~140us invariant to
//                    concurrency/arrangement/run-size). Fix: scatter into a
//                    60KB LDS staging buffer (bucket-ordered; LDS divergence
//                    costs only bank conflicts), then write out per-bucket
//                    runs with COALESCED wave stores (lane j -> gbase[b]+j).
//                    15360-edge chunks, 64.5KB LDS, 2 blocks/CU.
//     k_transform1 : standalone t1raw = x @ W1 (wave-per-row, W1 in regs,
//                    fp16 out, unscaled; dis applied in k_pass2). De-fused:
//                    every block of a kernel pays its LDS reservation, so
//                    the multisplit kernel can't host transform blocks.
//     k_pass2      : one block per bucket (512 thr): LDS 512-hist of sorted
//                    slice -> LDS scan -> rowptr = bbase[b]+prefix, dis =
//                    rsqrt(deg+1), scale t1raw *= dis, cursor-fill csr
//                    (csr stores stay within a 128KB L2-local window: cheap).
//   Layers (agg commutes with dense: A(XW)=(AX)W; all gathers width 16; the
//   16->32->16 chain and the classifier are fused into agg epilogues via
//   16-lane shuffle broadcasts -- h2 is never materialized):
//     t1  = (x @ W1) * dis                        (k_transform1 + k_pass2)
//     hs1 = relu(dis*gather(t1) + b1) * dis       (k_agg_rb)
//     t3  = (relu((dis*gather(hs1))@W2+b2)@W3)*dis (k_agg_mid, fused)
//     h   = relu(dis*gather(t3) + b3) -> outh
//     out = h @ Wc + bc               -> outc      (k_agg_out, fused)
//   Gathered arrays (t1, hs1, t3) are stored FP16: 3.2MB each -> fits the
//   4MB per-XCD L2. Random row reads are 32B, accumulation fp32. gather is
//   16-edge unrolled with 4 independent accumulators (~16 lines in flight).
//   No fp atomics anywhere. 9 kernel launches total.
// ---------------------------------------------------------------------------

#define MS_CHUNK 15360  // 60*256 edges per multisplit block (60KB staging)

__device__ __forceinline__ int blockScanExclusive256(int v, int* wsum) {
  int lane = threadIdx.x & 63;
  int wid  = threadIdx.x >> 6;
  int inc = v;
#pragma unroll
  for (int d = 1; d < 64; d <<= 1) {
    int y = __shfl_up(inc, d, 64);
    if (lane >= d) inc += y;
  }
  if (lane == 63) wsum[wid] = inc;
  __syncthreads();
  if (threadIdx.x == 0) {
    int s = 0;
#pragma unroll
    for (int w = 0; w < 4; ++w) { int t = wsum[w]; wsum[w] = s; s += t; }
  }
  __syncthreads();
  return inc - v + wsum[wid];
}

__device__ __forceinline__ int blockScanExclusive512(int v, int* wsum) {
  int lane = threadIdx.x & 63;
  int wid  = threadIdx.x >> 6;  // 0..7
  int inc = v;
#pragma unroll
  for (int d = 1; d < 64; d <<= 1) {
    int y = __shfl_up(inc, d, 64);
    if (lane >= d) inc += y;
  }
  if (lane == 63) wsum[wid] = inc;
  __syncthreads();
  if (threadIdx.x == 0) {
    int s = 0;
#pragma unroll
    for (int w = 0; w < 8; ++w) { int t = wsum[w]; wsum[w] = s; s += t; }
  }
  __syncthreads();
  return inc - v + wsum[wid];
}

// ---- per-block bucket histogram -> cntmat[g*nb + b] (g-major) ----
__global__ __launch_bounds__(256) void k_bhist(const int* __restrict__ ecol,
                                               int* __restrict__ cntmat,
                                               int e, int chunk, int nb) {
  __shared__ int h[256];
  h[threadIdx.x] = 0;
  __syncthreads();
  int g = blockIdx.x;
  int s0 = g * chunk;
  int s1 = min(e, s0 + chunk);
  int i = s0 + threadIdx.x;
  for (; i + 768 < s1; i += 1024) {
    int c0 = ecol[i], c1 = ecol[i + 256], c2 = ecol[i + 512], c3 = ecol[i + 768];
    atomicAdd(&h[c0 >> 9], 1);
    atomicAdd(&h[c1 >> 9], 1);
    atomicAdd(&h[c2 >> 9], 1);
    atomicAdd(&h[c3 >> 9], 1);
  }
  for (; i < s1; i += 256) atomicAdd(&h[ecol[i] >> 9], 1);
  __syncthreads();
  for (int b = threadIdx.x; b < nb; b += 256) cntmat[g * nb + b] = h[b];
}

// ---- per-bucket column scan over g; column total -> colsum[b] ----
__global__ __launch_bounds__(256) void k_colscan(int* __restrict__ cntmat,
                                                 int* __restrict__ colsum,
                                                 int G, int nb) {
  __shared__ int wsum[4];
  __shared__ int carry_s;
  int b = blockIdx.x;
  if (threadIdx.x == 0) carry_s = 0;
  __syncthreads();
  for (int base = 0; base < G; base += 256) {
    int i = base + threadIdx.x;
    int v = (i < G) ? cntmat[i * nb + b] : 0;
    int ex = blockScanExclusive256(v, wsum);
    int c = carry_s;
    __syncthreads();
    if (i < G) cntmat[i * nb + b] = ex + c;
    if (threadIdx.x == 255) carry_s = c + ex + v;
    __syncthreads();
  }
  if (threadIdx.x == 0) colsum[b] = carry_s;
}

// ---- bucket exclusive scan (1 block) ----
__global__ __launch_bounds__(256) void k_bscan(const int* __restrict__ colsum,
                                               int* __restrict__ bbase,
                                               int nb, int etot) {
  __shared__ int wsum[4];
  __shared__ int carry_s;
  if (threadIdx.x == 0) carry_s = 0;
  __syncthreads();
  for (int base = 0; base < nb; base += 256) {
    int i = base + threadIdx.x;
    int v = (i < nb) ? colsum[i] : 0;
    int ex = blockScanExclusive256(v, wsum);
    int c = carry_s;
    __syncthreads();
    if (i < nb) bbase[i] = ex + c;
    if (threadIdx.x == 255) carry_s = c + ex + v;
    __syncthreads();
  }
  if (threadIdx.x == 0) bbase[nb] = etot;
}

// ---- LDS-multisplit scatter: stage bucket-ordered in LDS, flush coalesced ----
__global__ __launch_bounds__(256) void k_scatter_ms(
    const int* __restrict__ erow, const int* __restrict__ ecol,
    const int* __restrict__ cntmat, const int* __restrict__ colsum,
    const int* __restrict__ bbase, unsigned* __restrict__ sorted,
    int e, int chunk, int nb, int G) {
  __shared__ unsigned staging[MS_CHUNK];  // 60KB
  __shared__ int lstart[256];
  __shared__ int lfill[256];
  __shared__ int gbase[256];
  __shared__ int wsum[4];
  int g = blockIdx.x;
  // local counts (into lfill temporarily) + global bases
  for (int b = threadIdx.x; b < nb; b += 256) {
    int cur = cntmat[g * nb + b];
    int nxt = (g + 1 < G) ? cntmat[(g + 1) * nb + b] : colsum[b];
    lfill[b] = nxt - cur;
    gbase[b] = bbase[b] + cur;
  }
  __syncthreads();
  // exclusive scan of local counts -> lstart
  int v = (threadIdx.x < nb) ? lfill[threadIdx.x] : 0;
  int ex = blockScanExclusive256(v, wsum);
  if (threadIdx.x < nb) lstart[threadIdx.x] = ex;
  __syncthreads();
  if (threadIdx.x < nb) lfill[threadIdx.x] = 0;
  __syncthreads();
  // scatter into LDS staging (divergence in LDS = bank conflicts only)
  int s0 = g * chunk;
  int s1 = min(e, s0 + chunk);
  int i = s0 + threadIdx.x;
  for (; i + 768 < s1; i += 1024) {
    int c0 = ecol[i],       c1 = ecol[i + 256], c2 = ecol[i + 512], c3 = ecol[i + 768];
    int r0 = erow[i],       r1 = erow[i + 256], r2 = erow[i + 512], r3 = erow[i + 768];
    int b0 = c0 >> 9, b1 = c1 >> 9, b2 = c2 >> 9, b3 = c3 >> 9;
    int p0 = atomicAdd(&lfill[b0], 1);
    int p1 = atomicAdd(&lfill[b1], 1);
    int p2 = atomicAdd(&lfill[b2], 1);
    int p3 = atomicAdd(&lfill[b3], 1);
    staging[lstart[b0] + p0] = ((unsigned)r0 << 9) | (unsigned)(c0 & 511);
    staging[lstart[b1] + p1] = ((unsigned)r1 << 9) | (unsigned)(c1 & 511);
    staging[lstart[b2] + p2] = ((unsigned)r2 << 9) | (unsigned)(c2 & 511);
    staging[lstart[b3] + p3] = ((unsigned)r3 << 9) | (unsigned)(c3 & 511);
  }
  for (; i < s1; i += 256) {
    int c = ecol[i];
    int b = c >> 9;
    int p = atomicAdd(&lfill[b], 1);
    staging[lstart[b] + p] = ((unsigned)erow[i] << 9) | (unsigned)(c & 511);
  }
  __syncthreads();
  // write-out: wave w handles buckets w, w+4, ... with coalesced stores
  int wid = threadIdx.x >> 6, L = threadIdx.x & 63;
  for (int b = wid; b < nb; b += 4) {
    int len = lfill[b];
    int ls = lstart[b], gb = gbase[b];
    for (int j = L; j < len; j += 64)
      sorted[gb + j] = staging[ls + j];
  }
}

// ---- layer-1 transform: wave per row, W1 (512x16) in regs, unscaled fp16 ----
__global__ __launch_bounds__(256) void k_transform1(
    const float* __restrict__ x, const float* __restrict__ W,
    __half* __restrict__ t1raw, int n) {
  int L = threadIdx.x & 63;
  int wid = blockIdx.x * 4 + (threadIdx.x >> 6);
  int nw = gridDim.x * 4;

  float w[8][16];
  const float4* W4 = reinterpret_cast<const float4*>(W);
#pragma unroll
  for (int i = 0; i < 4; ++i) {
#pragma unroll
    for (int c4 = 0; c4 < 4; ++c4) {
      float4 va = W4[(4 * L + i) * 4 + c4];
      w[i][c4 * 4 + 0] = va.x; w[i][c4 * 4 + 1] = va.y;
      w[i][c4 * 4 + 2] = va.z; w[i][c4 * 4 + 3] = va.w;
      float4 vb = W4[(256 + 4 * L + i) * 4 + c4];
      w[4 + i][c4 * 4 + 0] = vb.x; w[4 + i][c4 * 4 + 1] = vb.y;
      w[4 + i][c4 * 4 + 2] = vb.z; w[4 + i][c4 * 4 + 3] = vb.w;
    }
  }
  int col = ((L & 1) << 3) | ((L & 2) << 1) | ((L & 4) >> 1) | ((L & 8) >> 3);

  for (int r = wid; r < n; r += nw) {
    const float4* xr = reinterpret_cast<const float4*>(x + (size_t)r * 512);
    float4 v0 = xr[L];
    float4 v1 = xr[64 + L];
    float acc[16];
#pragma unroll
    for (int c = 0; c < 16; ++c) {
      float a = v0.x * w[0][c];
      a = fmaf(v0.y, w[1][c], a);
      a = fmaf(v0.z, w[2][c], a);
      a = fmaf(v0.w, w[3][c], a);
      a = fmaf(v1.x, w[4][c], a);
      a = fmaf(v1.y, w[5][c], a);
      a = fmaf(v1.z, w[6][c], a);
      a = fmaf(v1.w, w[7][c], a);
      acc[c] = a;
    }
#pragma unroll
    for (int j = 0; j < 8; ++j) {
      float send = (L & 1) ? acc[j] : acc[j + 8];
      float recv = __shfl_xor(send, 1, 64);
      acc[j] = ((L & 1) ? acc[j + 8] : acc[j]) + recv;
    }
#pragma unroll
    for (int j = 0; j < 4; ++j) {
      float send = (L & 2) ? acc[j] : acc[j + 4];
      float recv = __shfl_xor(send, 2, 64);
      acc[j] = ((L & 2) ? acc[j + 4] : acc[j]) + recv;
    }
#pragma unroll
    for (int j = 0; j < 2; ++j) {
      float send = (L & 4) ? acc[j] : acc[j + 2];
      float recv = __shfl_xor(send, 4, 64);
      acc[j] = ((L & 4) ? acc[j + 2] : acc[j]) + recv;
    }
    {
      float send = (L & 8) ? acc[0] : acc[1];
      float recv = __shfl_xor(send, 8, 64);
      acc[0] = ((L & 8) ? acc[1] : acc[0]) + recv;
    }
    float s = acc[0];
    s += __shfl_xor(s, 16, 64);
    s += __shfl_xor(s, 32, 64);
    if (L < 16) t1raw[r * 16 + col] = __float2half(s);
  }
}

// ---- pass2: per-bucket hist + scan + rowptr/dis + t1 scale + csr fill ----
__global__ __launch_bounds__(512) void k_pass2(const unsigned* __restrict__ sorted,
                                               const int* __restrict__ bbase,
                                               float* __restrict__ dis,
                                               int* __restrict__ rowptr,
                                               __half* __restrict__ t1,
                                               int* __restrict__ csr,
                                               int n, int etot) {
  __shared__ int hist[512];
  __shared__ int cur[512];
  __shared__ int wsum[8];
  int b = blockIdx.x;
  hist[threadIdx.x] = 0;
  __syncthreads();
  int s0 = bbase[b], s1 = bbase[b + 1];
  for (int i = s0 + threadIdx.x; i < s1; i += 512)
    atomicAdd(&hist[sorted[i] & 511], 1);
  __syncthreads();
  int j = threadIdx.x;
  int node = (b << 9) + j;
  int deg = hist[j];
  int ex = blockScanExclusive512(deg, wsum);
  float dv = rsqrtf((float)(deg + 1));  // +1 self loop
  cur[j] = s0 + ex;
  if (node < n) {
    dis[node] = dv;
    rowptr[node] = s0 + ex;
    // scale this node's t1 row in place (bucket rows contiguous, streaming)
    __half2* t2 = reinterpret_cast<__half2*>(t1 + ((size_t)node << 4));
#pragma unroll
    for (int q = 0; q < 8; ++q) {
      float2 fv = __half22float2(t2[q]);
      fv.x *= dv; fv.y *= dv;
      t2[q] = __float22half2_rn(fv);
    }
  }
  if (b == 0 && threadIdx.x == 0) rowptr[n] = etot;
  __syncthreads();
  for (int i = s0 + threadIdx.x; i < s1; i += 512) {
    unsigned v = sorted[i];
    int pos = atomicAdd(&cur[v & 511], 1);
    csr[pos] = (int)(v >> 9);
  }
}

// ---- common gather: acc = self + sum of neighbor rows (fp16 rows, fp32
//      accumulate). 16-edge unroll, 4 independent accumulators. ----
__device__ __forceinline__ float gather16(const __half* __restrict__ hs,
                                          const int* __restrict__ rowptr,
                                          const int* __restrict__ csr,
                                          int node, int f) {
  float acc0 = __half2float(hs[(node << 4) + f]);  // self loop (pre-scaled)
  int e0 = rowptr[node], e1 = rowptr[node + 1];
  int e = e0;
  float acc1 = 0.f, acc2 = 0.f, acc3 = 0.f;
  for (; e + 16 <= e1; e += 16) {
    int r0  = csr[e + 0],  r1  = csr[e + 1],  r2  = csr[e + 2],  r3  = csr[e + 3];
    int r4  = csr[e + 4],  r5  = csr[e + 5],  r6  = csr[e + 6],  r7  = csr[e + 7];
    int r8  = csr[e + 8],  r9  = csr[e + 9],  r10 = csr[e + 10], r11 = csr[e + 11];
    int r12 = csr[e + 12], r13 = csr[e + 13], r14 = csr[e + 14], r15 = csr[e + 15];
    __half v0  = hs[(r0  << 4) + f], v1  = hs[(r1  << 4) + f];
    __half v2  = hs[(r2  << 4) + f], v3  = hs[(r3  << 4) + f];
    __half v4  = hs[(r4  << 4) + f], v5  = hs[(r5  << 4) + f];
    __half v6  = hs[(r6  << 4) + f], v7  = hs[(r7  << 4) + f];
    __half v8  = hs[(r8  << 4) + f], v9  = hs[(r9  << 4) + f];
    __half v10 = hs[(r10 << 4) + f], v11 = hs[(r11 << 4) + f];
    __half v12 = hs[(r12 << 4) + f], v13 = hs[(r13 << 4) + f];
    __half v14 = hs[(r14 << 4) + f], v15 = hs[(r15 << 4) + f];
    acc0 += (__half2float(v0)  + __half2float(v1))  + (__half2float(v2)  + __half2float(v3));
    acc1 += (__half2float(v4)  + __half2float(v5))  + (__half2float(v6)  + __half2float(v7));
    acc2 += (__half2float(v8)  + __half2float(v9))  + (__half2float(v10) + __half2float(v11));
    acc3 += (__half2float(v12) + __half2float(v13)) + (__half2float(v14) + __half2float(v15));
  }
  for (; e + 4 <= e1; e += 4) {
    int r0 = csr[e + 0], r1 = csr[e + 1], r2 = csr[e + 2], r3 = csr[e + 3];
    float v0 = __half2float(hs[(r0 << 4) + f]), v1 = __half2float(hs[(r1 << 4) + f]);
    float v2 = __half2float(hs[(r2 << 4) + f]), v3 = __half2float(hs[(r3 << 4) + f]);
    acc0 += (v0 + v1) + (v2 + v3);
  }
  for (; e < e1; ++e) acc0 += __half2float(hs[(csr[e] << 4) + f]);
  return (acc0 + acc1) + (acc2 + acc3);
}

// out = relu(dis*acc + b) * dis   (layer-1 agg, prescaled for next gather)
__global__ __launch_bounds__(256) void k_agg_rb(
    const __half* __restrict__ hs, const int* __restrict__ rowptr,
    const int* __restrict__ csr, const float* __restrict__ dis,
    const float* __restrict__ b, __half* __restrict__ out, int n) {
  int node = blockIdx.x * 16 + threadIdx.x / 16;
  int f = threadIdx.x % 16;
  if (node >= n) return;
  float acc = gather16(hs, rowptr, csr, node, f);
  float d = dis[node];
  float t = fmaxf(fmaf(d, acc, b[f]), 0.f);
  out[(node << 4) + f] = __float2half(t * d);
}

// mid: t3 = (relu((dis*acc)@W2 + b2) @ W3) * dis   -- 16->32->16 in-register
__global__ __launch_bounds__(256) void k_agg_mid(
    const __half* __restrict__ hs, const int* __restrict__ rowptr,
    const int* __restrict__ csr, const float* __restrict__ dis,
    const float* __restrict__ W2, const float* __restrict__ b2,
    const float* __restrict__ W3, __half* __restrict__ out, int n) {
  __shared__ float w2s[512];  // [16][32]
  __shared__ float w3s[512];  // [32][16]
  __shared__ float b2s[32];
  for (int i = threadIdx.x; i < 512; i += 256) { w2s[i] = W2[i]; w3s[i] = W3[i]; }
  if (threadIdx.x < 32) b2s[threadIdx.x] = b2[threadIdx.x];
  __syncthreads();
  int node = blockIdx.x * 16 + threadIdx.x / 16;
  int f = threadIdx.x % 16;
  if (node >= n) return;
  float acc = gather16(hs, rowptr, csr, node, f);
  float d = dis[node];
  float v = d * acc;  // g2[f]
  int base = threadIdx.x & 48;  // 16-group base lane in wave
  float a0 = b2s[f], a1 = b2s[f + 16];
#pragma unroll
  for (int k = 0; k < 16; ++k) {
    float vk = __shfl(v, base + k, 64);
    a0 = fmaf(vk, w2s[k * 32 + f], a0);
    a1 = fmaf(vk, w2s[k * 32 + 16 + f], a1);
  }
  a0 = fmaxf(a0, 0.f);
  a1 = fmaxf(a1, 0.f);
  float t = 0.f;
#pragma unroll
  for (int c = 0; c < 16; ++c) {
    float h0 = __shfl(a0, base + c, 64);
    float h1 = __shfl(a1, base + c, 64);
    t = fmaf(h0, w3s[c * 16 + f], t);
    t = fmaf(h1, w3s[(c + 16) * 16 + f], t);
  }
  out[(node << 4) + f] = __float2half(t * d);
}

// final: h = relu(dis*acc + b3) -> outh;  out = h@Wc + bc -> outc
__global__ __launch_bounds__(256) void k_agg_out(
    const __half* __restrict__ hs, const int* __restrict__ rowptr,
    const int* __restrict__ csr, const float* __restrict__ dis,
    const float* __restrict__ b3, const float* __restrict__ Wc,
    const float* __restrict__ bc, float* __restrict__ outh,
    float* __restrict__ outc, int n) {
  __shared__ float wcs[256];  // [16][16]
  __shared__ float b3s[16];
  __shared__ float bcs[16];
  if (threadIdx.x < 256) wcs[threadIdx.x] = Wc[threadIdx.x];
  if (threadIdx.x < 16) { b3s[threadIdx.x] = b3[threadIdx.x]; bcs[threadIdx.x] = bc[threadIdx.x]; }
  __syncthreads();
  int node = blockIdx.x * 16 + threadIdx.x / 16;
  int f = threadIdx.x % 16;
  if (node >= n) return;
  float acc = gather16(hs, rowptr, csr, node, f);
  float d = dis[node];
  float h = fmaxf(fmaf(d, acc, b3s[f]), 0.f);
  outh[(node << 4) + f] = h;
  int base = threadIdx.x & 48;
  float o = bcs[f];
#pragma unroll
  for (int k = 0; k < 16; ++k) {
    float hk = __shfl(h, base + k, 64);
    o = fmaf(hk, wcs[k * 16 + f], o);
  }
  outc[(node << 4) + f] = o;
}

extern "C" void kernel_launch(void* const* d_in, const int* in_sizes, int n_in,
                              void* d_out, int out_size, void* d_ws, size_t ws_size,
                              hipStream_t stream) {
  (void)n_in; (void)out_size;
  const float* x  = (const float*)d_in[0];
  const int*   ei = (const int*)d_in[1];
  const float* W1 = (const float*)d_in[2];
  const float* b1 = (const float*)d_in[3];
  const float* W2 = (const float*)d_in[4];
  const float* b2 = (const float*)d_in[5];
  const float* W3 = (const float*)d_in[6];
  const float* b3 = (const float*)d_in[7];
  const float* Wc = (const float*)d_in[8];
  const float* bc = (const float*)d_in[9];

  const int F = 512;
  int N = in_sizes[0] / F;
  int E = in_sizes[1] / 2;
  const int* erow = ei;        // sources
  const int* ecol = ei + E;    // targets
  int NB = (N + 511) >> 9;     // buckets of 512 nodes (N<=131072)
  const int chunk = MS_CHUNK;  // 15360 edges per multisplit block
  int GS = (E + chunk - 1) / chunk;

  auto align = [](size_t v) { return (v + 255) & ~(size_t)255; };
  char* p = (char*)d_ws;
  int*   cntmat = (int*)p;   p += align((size_t)GS * NB * 4);
  int*   colsum = (int*)p;   p += align(256 * 4);
  int*   bbase  = (int*)p;   p += align(257 * 4);
  float* dis    = (float*)p; p += align((size_t)N * 4);
  int*   rowptr = (int*)p;   p += align(((size_t)N + 1) * 4);
  int*   csr    = (int*)p;   p += align((size_t)E * 4);
  unsigned* sorted = (unsigned*)p; p += align((size_t)E * 4);
  // bufA does not alias sorted (sorted is live while t1 is written)
  __half* bufA = (__half*)p; p += align((size_t)N * 16 * 2);
  __half* bufB = (__half*)p; p += align((size_t)N * 16 * 2);
  if ((size_t)(p - (char*)d_ws) > ws_size) return;  // fail visibly

  float* outc = (float*)d_out;                   // [N,16] classifier out
  float* outh = (float*)d_out + (size_t)N * 16;  // [N,16] h

  // ---- CSR build ----
  k_bhist<<<GS, 256, 0, stream>>>(ecol, cntmat, E, chunk, NB);
  k_colscan<<<NB, 256, 0, stream>>>(cntmat, colsum, GS, NB);
  k_bscan<<<1, 256, 0, stream>>>(colsum, bbase, NB, E);
  k_scatter_ms<<<GS, 256, 0, stream>>>(erow, ecol, cntmat, colsum, bbase,
                                       sorted, E, chunk, NB, GS);
  // t1raw = x@W1 (unscaled fp16)
  k_transform1<<<2048, 256, 0, stream>>>(x, W1, bufA, N);
  // hist+scan+rowptr+dis, t1 *= dis, csr fill
  k_pass2<<<NB, 512, 0, stream>>>(sorted, bbase, dis, rowptr, bufA, csr, N, E);

  // ---- layers ----
  // hs1 = relu(dis*agg(t1)+b1)*dis  (fp16)
  k_agg_rb<<<(N + 15) / 16, 256, 0, stream>>>(bufA, rowptr, csr, dis, b1, bufB, N);
  // t3 = (relu((dis*agg(hs1))@W2+b2)@W3)*dis  (fp16)
  k_agg_mid<<<(N + 15) / 16, 256, 0, stream>>>(bufB, rowptr, csr, dis, W2, b2, W3, bufA, N);
  // h = relu(dis*agg(t3)+b3) -> outh;  out = h@Wc+bc -> outc  (fp32 outputs)
  k_agg_out<<<(N + 15) / 16, 256, 0, stream>>>(bufA, rowptr, csr, dis, b3, Wc, bc, outh, outc, N);
}